// Round 12
// baseline (2116.140 us; speedup 1.0000x reference)
//
#include <hip/hip_runtime.h>
#include <math.h>

#define D 512
#define NH 8
#define DH 64
#define HID 2048
#define NL 6
#define SEQ 512
#define BATCH 4
#define MROWS (BATCH * SEQ)   // 2048
#define NVT 16000
#define LNEPS 1e-5f

typedef __attribute__((ext_vector_type(8))) short short8;
typedef __attribute__((ext_vector_type(4))) float f32x4;

// ---------------------------------------------------------------------------
// bf16 RTNE helpers
// ---------------------------------------------------------------------------
__device__ __forceinline__ ushort bf16_rtne(float f) {
    uint u = __builtin_bit_cast(uint, f);
    return (ushort)((u + 0x7fffu + ((u >> 16) & 1u)) >> 16);
}
__device__ __forceinline__ uint rtne2(float a, float b) {
    return (uint)bf16_rtne(a) | ((uint)bf16_rtne(b) << 16);
}

// ---------------------------------------------------------------------------
// Weight transpose + bf16 convert: src[K][N] fp32 -> dst[N][K] bf16 (rtne).
// 64x64 tiles via LDS [64][65]. z batches over zstride (validated round 6).
// ---------------------------------------------------------------------------
__global__ __launch_bounds__(256) void wsplit_kernel(const float* __restrict__ src,
                                                     ushort* __restrict__ dst,
                                                     int K, int N, size_t zstride) {
    __shared__ float T[64][65];
    src += (size_t)blockIdx.z * zstride;
    dst += (size_t)blockIdx.z * zstride;
    const int t = threadIdx.x;
    const int n0 = blockIdx.x * 64;
    const int k0 = blockIdx.y * 64;
    {
        const int kr = t >> 4, nc = (t & 15) * 4;
#pragma unroll
        for (int i = 0; i < 4; ++i) {
            float4 v = *(const float4*)&src[(size_t)(k0 + kr + 16 * i) * N + n0 + nc];
            T[kr + 16 * i][nc + 0] = v.x;
            T[kr + 16 * i][nc + 1] = v.y;
            T[kr + 16 * i][nc + 2] = v.z;
            T[kr + 16 * i][nc + 3] = v.w;
        }
    }
    __syncthreads();
    const int n = t >> 2;
    const int kc = (t & 3) * 16;
    uint h[8];
#pragma unroll
    for (int i = 0; i < 8; ++i)
        h[i] = rtne2(T[kc + 2 * i][n], T[kc + 2 * i + 1][n]);
    ushort* dh = &dst[(size_t)(n0 + n) * K + k0 + kc];
    *(uint4*)(dh + 0) = uint4{h[0], h[1], h[2], h[3]};
    *(uint4*)(dh + 8) = uint4{h[4], h[5], h[6], h[7]};
}

// ---------------------------------------------------------------------------
// bf16 MFMA GEMM (round-6 single-buffer structure — fastest measured).
// C[M,N] = A[M,K] @ W[K,N] + bias, opt ReLU, opt bf16 output.
// BOTH operands bf16 in memory: A [M][K] (activation mirror), W^T [N][K].
// Identity consecutive-k LDS rows both sides (validated r4); fragment =
// 1 ds_read_b128 at [row][8*(lane>>4)], rows padded to 40 ushort / 80 B.
// BK=32, 256 thr = 4 waves (2x2), wave tile (BM/2)x(BN/2), 16x16x32 MFMA.
// grid (M/BM, N/BN, z): m-major. z-batch: W/bias/C slices; A = z ? A1 : A0.
// ---------------------------------------------------------------------------
template <int BM, int BN, bool RELU, bool OBF16>
__global__ __launch_bounds__(256) void gemm_mfma(const ushort* __restrict__ A0,
                                                 const ushort* __restrict__ A1,
                                                 const ushort* __restrict__ WT,
                                                 const float* __restrict__ bias,
                                                 void* __restrict__ Cv,
                                                 int M, int N, int K,
                                                 size_t wz, size_t cz) {
    constexpr int FM = BM / 32;
    constexpr int FN = BN / 32;
    constexpr int EA = BM / 64;          // uint4 staging loads / thread (A)
    constexpr int EB = BN / 64;          // uint4 staging loads / thread (B)
    constexpr int AROW = 40;

    __shared__ ushort Ah[BM * AROW];
    __shared__ ushort Bh[BN * AROW];

    const ushort* A = (blockIdx.z == 0) ? A0 : A1;
    WT += (size_t)blockIdx.z * wz;
    bias += (size_t)blockIdx.z * (size_t)N;

    const int tid = threadIdx.x;
    const int lane = tid & 63;
    const int wv = tid >> 6;
    const int wm = wv >> 1, wn = wv & 1;
    const int bm = blockIdx.x * BM;
    const int bn = blockIdx.y * BN;

    const int s_r = tid >> 2;            // row 0..63 (+64i)
    const int s_k8 = (tid & 3) * 8;      // k-chunk of 8

    const ushort* aP[EA];
#pragma unroll
    for (int i = 0; i < EA; ++i)
        aP[i] = A + (size_t)(bm + 64 * i + s_r) * K + s_k8;
    const ushort* bP[EB];
#pragma unroll
    for (int i = 0; i < EB; ++i)
        bP[i] = WT + (size_t)(bn + 64 * i + s_r) * K + s_k8;

    uint4 apre[EA], bpre[EB];
#pragma unroll
    for (int i = 0; i < EA; ++i) apre[i] = *(const uint4*)(aP[i]);
#pragma unroll
    for (int i = 0; i < EB; ++i) bpre[i] = *(const uint4*)(bP[i]);

    f32x4 acc[FM][FN] = {};
    const int NT = K >> 5;
    const int g8 = (lane >> 4) * 8;

    for (int kt = 0; kt < NT; ++kt) {
        // ---- stage prefetched regs into LDS (pure uint4 copies) ----
#pragma unroll
        for (int i = 0; i < EA; ++i)
            *(uint4*)&Ah[(64 * i + s_r) * AROW + s_k8] = apre[i];
#pragma unroll
        for (int i = 0; i < EB; ++i)
            *(uint4*)&Bh[(64 * i + s_r) * AROW + s_k8] = bpre[i];
        __syncthreads();

        // ---- prefetch next k-tile ----
        if (kt + 1 < NT) {
            const int ko = (kt + 1) * 32;
#pragma unroll
            for (int i = 0; i < EA; ++i) apre[i] = *(const uint4*)(aP[i] + ko);
#pragma unroll
            for (int i = 0; i < EB; ++i) bpre[i] = *(const uint4*)(bP[i] + ko);
        }

        // ---- fragment reads (one b128 each) + MFMA ----
        short8 af[FM], bf[FN];
#pragma unroll
        for (int mi = 0; mi < FM; ++mi)
            af[mi] = *(const short8*)&Ah[(wm * (BM / 2) + mi * 16 + (lane & 15)) * AROW + g8];
#pragma unroll
        for (int ni = 0; ni < FN; ++ni)
            bf[ni] = *(const short8*)&Bh[(wn * (BN / 2) + ni * 16 + (lane & 15)) * AROW + g8];

#pragma unroll
        for (int ni = 0; ni < FN; ++ni)
#pragma unroll
            for (int mi = 0; mi < FM; ++mi)
                acc[mi][ni] = __builtin_amdgcn_mfma_f32_16x16x32_bf16(af[mi], bf[ni], acc[mi][ni], 0, 0, 0);
        __syncthreads();
    }

    // ---- epilogue: C/D layout col=lane&15, row=(lane>>4)*4+reg ----
#pragma unroll
    for (int ni = 0; ni < FN; ++ni) {
        const int col = bn + wn * (BN / 2) + ni * 16 + (lane & 15);
        const float bv = bias[col];
#pragma unroll
        for (int mi = 0; mi < FM; ++mi) {
            const int r0 = bm + wm * (BM / 2) + mi * 16 + (lane >> 4) * 4;
#pragma unroll
            for (int r = 0; r < 4; ++r) {
                float v = acc[mi][ni][r] + bv;
                if (RELU) v = fmaxf(v, 0.0f);
                if (OBF16) {
                    ushort* C = (ushort*)Cv + (size_t)blockIdx.z * cz;
                    C[(size_t)(r0 + r) * N + col] = bf16_rtne(v);
                } else {
                    float* C = (float*)Cv + (size_t)blockIdx.z * cz;
                    C[(size_t)(r0 + r) * N + col] = v;
                }
            }
        }
    }
}

// ---------------------------------------------------------------------------
// MFMA flash attention — bf16 inputs/outputs (rounding points identical to
// the validated round-5 kernel; conversion moved to producers).
// MODE 0: key masked where srctok==PAD; MODE 1: causal | tgttok==PAD.
// ---------------------------------------------------------------------------
template <int MODE>
__global__ __launch_bounds__(256) void attn_mfma(const ushort* __restrict__ Qm,
                                                 const ushort* __restrict__ Km,
                                                 const ushort* __restrict__ Vm,
                                                 const int* __restrict__ toks,
                                                 ushort* __restrict__ Om) {
    constexpr int ROW = 72;
    __shared__ ushort Kl[64 * ROW];
    __shared__ ushort Vl[64 * ROW];
    __shared__ ushort Pl[4][16 * ROW];

    const int tid = threadIdx.x;
    const int lane = tid & 63;
    const int w = tid >> 6;
    const int g = lane >> 4, c = lane & 15;
    const int b = blockIdx.y >> 3, h = blockIdx.y & 7;
    const int q0 = blockIdx.x * 64;
    const size_t base = (size_t)b * SEQ * D + h * DH;
    const int* tokp = toks + b * SEQ;

    short8 qf[2];
    {
        const ushort* qp = Qm + base + (size_t)(q0 + w * 16 + c) * D + g * 8;
        qf[0] = *(const short8*)(qp);
        qf[1] = *(const short8*)(qp + 32);
    }

    const int sk_key = tid >> 2, sk_dh = (tid & 3) * 16;
    const int sv_dh = tid >> 2, sv_key = (tid & 3) * 16;
    const ushort* kP = Km + base + (size_t)sk_key * D + sk_dh;
    const ushort* vP = Vm + base + (size_t)sv_key * D + sv_dh;

    uint4 kreg[2];
    ushort vreg[16];
    kreg[0] = *(const uint4*)(kP);
    kreg[1] = *(const uint4*)(kP + 8);
#pragma unroll
    for (int i = 0; i < 16; ++i) vreg[i] = vP[(size_t)i * D];

    f32x4 Ov[4] = {};
    float m_r[4], l_r[4];
#pragma unroll
    for (int r = 0; r < 4; ++r) { m_r[r] = -1e30f; l_r[r] = 0.f; }

    for (int kt = 0; kt < SEQ / 64; ++kt) {
        {
            union { ushort us[16]; uint4 u4[2]; } uv;
#pragma unroll
            for (int i = 0; i < 16; ++i) uv.us[i] = vreg[i];
            *(uint4*)&Kl[sk_key * ROW + sk_dh + 0] = kreg[0];
            *(uint4*)&Kl[sk_key * ROW + sk_dh + 8] = kreg[1];
            *(uint4*)&Vl[sv_dh * ROW + sv_key + 0] = uv.u4[0];
            *(uint4*)&Vl[sv_dh * ROW + sv_key + 8] = uv.u4[1];
        }
        __syncthreads();

        if (kt + 1 < SEQ / 64) {
            const size_t adv = (size_t)(kt + 1) * 64 * D;
            kreg[0] = *(const uint4*)(kP + adv);
            kreg[1] = *(const uint4*)(kP + adv + 8);
#pragma unroll
            for (int i = 0; i < 16; ++i) vreg[i] = vP[adv + (size_t)i * D];
        }

        f32x4 sc[4] = {};
#pragma unroll
        for (int ni = 0; ni < 4; ++ni)
#pragma unroll
            for (int kc = 0; kc < 2; ++kc) {
                short8 kf = *(const short8*)&Kl[(ni * 16 + c) * ROW + kc * 32 + g * 8];
                sc[ni] = __builtin_amdgcn_mfma_f32_16x16x32_bf16(qf[kc], kf, sc[ni], 0, 0, 0);
            }

        const int k0g = kt * 64;
        int tk[4];
#pragma unroll
        for (int ni = 0; ni < 4; ++ni) tk[ni] = tokp[k0g + ni * 16 + c];
        float p[4][4], tm[4];
#pragma unroll
        for (int r = 0; r < 4; ++r) tm[r] = -1e30f;
#pragma unroll
        for (int ni = 0; ni < 4; ++ni) {
            const int key = k0g + ni * 16 + c;
            const bool colmask = (tk[ni] == 0);
#pragma unroll
            for (int r = 0; r < 4; ++r) {
                bool msk = colmask;
                if (MODE == 1) msk = msk || (key > q0 + w * 16 + 4 * g + r);
                const float s = msk ? -1e30f : sc[ni][r] * 0.125f;
                p[ni][r] = s;
                tm[r] = fmaxf(tm[r], s);
            }
        }
#pragma unroll
        for (int off = 1; off < 16; off <<= 1)
#pragma unroll
            for (int r = 0; r < 4; ++r) tm[r] = fmaxf(tm[r], __shfl_xor(tm[r], off, 16));
        float f_r[4], ts[4];
#pragma unroll
        for (int r = 0; r < 4; ++r) {
            const float mn = fmaxf(m_r[r], tm[r]);
            f_r[r] = __expf(m_r[r] - mn);
            m_r[r] = mn;
            ts[r] = 0.f;
        }
#pragma unroll
        for (int ni = 0; ni < 4; ++ni)
#pragma unroll
            for (int r = 0; r < 4; ++r) {
                const float e = (p[ni][r] <= -1e29f) ? 0.f : __expf(p[ni][r] - m_r[r]);
                p[ni][r] = e;
                ts[r] += e;
            }
#pragma unroll
        for (int off = 1; off < 16; off <<= 1)
#pragma unroll
            for (int r = 0; r < 4; ++r) ts[r] += __shfl_xor(ts[r], off, 16);
#pragma unroll
        for (int r = 0; r < 4; ++r) l_r[r] = l_r[r] * f_r[r] + ts[r];
#pragma unroll
        for (int nd = 0; nd < 4; ++nd)
#pragma unroll
            for (int r = 0; r < 4; ++r) Ov[nd][r] *= f_r[r];

#pragma unroll
        for (int ni = 0; ni < 4; ++ni)
#pragma unroll
            for (int r = 0; r < 4; ++r)
                Pl[w][(4 * r + g) * ROW + ni * 16 + c] = bf16_rtne(p[ni][r]);
        asm volatile("s_waitcnt lgkmcnt(0)" ::: "memory");
        __builtin_amdgcn_sched_barrier(0);

        const int pr = ((c & 3) << 2) | (c >> 2);
#pragma unroll
        for (int kc = 0; kc < 2; ++kc) {
            short8 pf = *(const short8*)&Pl[w][pr * ROW + kc * 32 + g * 8];
#pragma unroll
            for (int nd = 0; nd < 4; ++nd) {
                short8 vf = *(const short8*)&Vl[(nd * 16 + c) * ROW + kc * 32 + g * 8];
                Ov[nd] = __builtin_amdgcn_mfma_f32_16x16x32_bf16(pf, vf, Ov[nd], 0, 0, 0);
            }
        }
        __syncthreads();
    }

    float inv[4];
#pragma unroll
    for (int r = 0; r < 4; ++r) inv[r] = 1.0f / l_r[r];
    ushort* op = Om + base;
#pragma unroll
    for (int nd = 0; nd < 4; ++nd)
#pragma unroll
        for (int r = 0; r < 4; ++r)
            op[(size_t)(q0 + w * 16 + 4 * g + r) * D + nd * 16 + c] =
                bf16_rtne(Ov[nd][r] * inv[r]);
}

// ---------------------------------------------------------------------------
// Embedding + positional encoding, fp32 + bf16 mirror, both seqs (y selects)
// ---------------------------------------------------------------------------
__global__ __launch_bounds__(128) void embed2_kernel(const int* __restrict__ src,
                                                     const int* __restrict__ tgt,
                                                     const float* __restrict__ es,
                                                     const float* __restrict__ et,
                                                     float* __restrict__ xe,
                                                     float* __restrict__ xd,
                                                     ushort* __restrict__ xeb,
                                                     ushort* __restrict__ xdb) {
    const int which = blockIdx.y;
    const int* toks = which ? tgt : src;
    const float* emb = which ? et : es;
    float* out = which ? xd : xe;
    ushort* outb = which ? xdb : xeb;
    const int row = blockIdx.x;
    const int s = row & (SEQ - 1);
    const int tok = toks[row];
    const int d = threadIdx.x * 4;
    float4 e = *(const float4*)&emb[tok * D + d];
    float r[4];
#pragma unroll
    for (int i = 0; i < 4; i += 2) {
        const int dd = d + i;
        const float dv = expf((float)dd * (-9.210340371976184f / (float)D));
        const float ang = (float)s * dv;
        r[i] = sinf(ang);
        r[i + 1] = cosf(ang);
    }
    float4 o;
    o.x = e.x + r[0]; o.y = e.y + r[1]; o.z = e.z + r[2]; o.w = e.w + r[3];
    *(float4*)&out[row * D + d] = o;
    *(uint2*)&outb[row * D + d] = uint2{rtne2(o.x, o.y), rtne2(o.z, o.w)};
}

// ---------------------------------------------------------------------------
// Residual add + LayerNorm, in place on fp32 x, dual-writes bf16 mirror xb
// ---------------------------------------------------------------------------
__global__ __launch_bounds__(128) void add_ln_kernel(float* __restrict__ x,
                                                     ushort* __restrict__ xb,
                                                     const float* __restrict__ r,
                                                     const float* __restrict__ g,
                                                     const float* __restrict__ b) {
    const int row = blockIdx.x;
    const int t = threadIdx.x;
    const int d = t * 4;
    float4 xv = *(const float4*)&x[row * D + d];
    float4 rv = *(const float4*)&r[row * D + d];
    float4 v;
    v.x = xv.x + rv.x; v.y = xv.y + rv.y; v.z = xv.z + rv.z; v.w = xv.w + rv.w;
    float s = v.x + v.y + v.z + v.w;
    float s2 = v.x * v.x + v.y * v.y + v.z * v.z + v.w * v.w;
#pragma unroll
    for (int off = 32; off > 0; off >>= 1) {
        s += __shfl_down(s, off);
        s2 += __shfl_down(s2, off);
    }
    __shared__ float sh[4];
    if ((t & 63) == 0) { sh[(t >> 6) * 2] = s; sh[(t >> 6) * 2 + 1] = s2; }
    __syncthreads();
    s = sh[0] + sh[2];
    s2 = sh[1] + sh[3];
    const float mean = s * (1.0f / D);
    const float var = s2 * (1.0f / D) - mean * mean;
    const float rstd = rsqrtf(var + LNEPS);
    float4 gv = *(const float4*)&g[d];
    float4 bv = *(const float4*)&b[d];
    float4 o;
    o.x = (v.x - mean) * rstd * gv.x + bv.x;
    o.y = (v.y - mean) * rstd * gv.y + bv.y;
    o.z = (v.z - mean) * rstd * gv.z + bv.z;
    o.w = (v.w - mean) * rstd * gv.w + bv.w;
    *(float4*)&x[row * D + d] = o;
    *(uint2*)&xb[row * D + d] = uint2{rtne2(o.x, o.y), rtne2(o.z, o.w)};
}

// ---------------------------------------------------------------------------
// Host-side orchestration
// ---------------------------------------------------------------------------
extern "C" void kernel_launch(void* const* d_in, const int* in_sizes, int n_in,
                              void* d_out, int out_size, void* d_ws, size_t ws_size,
                              hipStream_t stream) {
    const int* src = (const int*)d_in[0];
    const int* tgt = (const int*)d_in[1];
    const float* emb_src = (const float*)d_in[2];
    const float* emb_tgt = (const float*)d_in[3];
    const float* enc_attn_w = (const float*)d_in[4];
    const float* enc_attn_b = (const float*)d_in[5];
    const float* enc_ff_w1 = (const float*)d_in[6];
    const float* enc_ff_b1 = (const float*)d_in[7];
    const float* enc_ff_w2 = (const float*)d_in[8];
    const float* enc_ff_b2 = (const float*)d_in[9];
    const float* enc_ln_g = (const float*)d_in[10];
    const float* enc_ln_b = (const float*)d_in[11];
    const float* dec_attn_w = (const float*)d_in[12];
    const float* dec_attn_b = (const float*)d_in[13];
    const float* dec_ff_w1 = (const float*)d_in[14];
    const float* dec_ff_b1 = (const float*)d_in[15];
    const float* dec_ff_w2 = (const float*)d_in[16];
    const float* dec_ff_b2 = (const float*)d_in[17];
    const float* dec_ln_g = (const float*)d_in[18];
    const float* dec_ln_b = (const float*)d_in[19];
    const float* fc_w = (const float*)d_in[20];
    const float* fc_b = (const float*)d_in[21];
    float* out = (float*)d_out;

    float* ws = (float*)d_ws;
    const size_t NTOK = (size_t)MROWS * D;   // 1M elems
    // fp32: residual streams + GEMM fp32 temp
    float* xe = ws;
    float* xd = xe + NTOK;
    float* tb = xd + NTOK;
    // bf16 mirrors / activations
    ushort* xeb = (ushort*)(tb + NTOK);
    ushort* xdb = xeb + NTOK;
    ushort* qbb = xdb + NTOK;     // q,k,v contiguous (z-batched QKV out)
    ushort* kbb = qbb + NTOK;
    ushort* vbb = kbb + NTOK;
    ushort* abb = vbb + NTOK;     // attention output (bf16)
    ushort* hbb = abb + NTOK;     // ffn hidden (bf16), 4*NTOK
    ushort* u0 = hbb + 4 * NTOK;
    const size_t DD = (size_t)D * D;
    const size_t FCE = (size_t)D * NVT;
    const size_t act_bytes = NTOK * (3 * 4 + 10 * 2);
    const bool batched = ws_size >= act_bytes + (168 * DD + FCE) * 2 + 1024;

    ushort *bEncA, *bEncF1, *bEncF2, *bDecA, *bDecF1, *bDecF2, *bFC;
    ushort *wA = nullptr, *wF1 = nullptr, *wF2 = nullptr;
    if (batched) {
        bEncA = u0;
        bEncF1 = bEncA + 24 * DD;
        bEncF2 = bEncF1 + 24 * DD;
        bDecA = bEncF2 + 24 * DD;
        bDecF1 = bDecA + 48 * DD;
        bDecF2 = bDecF1 + 24 * DD;
        bFC = bDecF2 + 24 * DD;
    } else {
        wA = u0;
        wF1 = wA + 8 * DD;
        wF2 = wF1 + 4 * DD;
        bFC = wF2 + 4 * DD;
        bEncA = bEncF1 = bEncF2 = bDecA = bDecF1 = bDecF2 = nullptr;
    }

    auto tr = [&](const float* w, ushort* dh, int K, int N, int nz) {
        dim3 grid(N / 64, K / 64, nz);
        wsplit_kernel<<<grid, 256, 0, stream>>>(w, dh, K, N, (size_t)K * N);
    };
    auto gemm64f = [&](const ushort* A, const ushort* WT,
                       const float* bias, float* C, int M, int N, int K) {
        dim3 grid(M / 64, N / 64, 1);
        gemm_mfma<64, 64, false, false><<<grid, 256, 0, stream>>>(A, A, WT, bias, C, M, N, K, 0, 0);
    };
    auto gemm128_relu_b = [&](const ushort* A, const ushort* WT,
                              const float* bias, ushort* C, int M, int N, int K) {
        dim3 grid(M / 128, N / 128, 1);
        gemm_mfma<128, 128, true, true><<<grid, 256, 0, stream>>>(A, A, WT, bias, C, M, N, K, 0, 0);
    };
    // fused Q,K,V projection, 64^2 tiles, bf16 out into qbb/kbb/vbb
    auto gemm_qkv = [&](const ushort* Aq, const ushort* Akv,
                        const ushort* WT, const float* bi) {
        dim3 grid(MROWS / 64, D / 64, 3);
        gemm_mfma<64, 64, false, true><<<grid, 256, 0, stream>>>(Aq, Akv, WT, bi, qbb,
                                                                 MROWS, D, D, DD, NTOK);
    };

    if (batched) {
        tr(enc_attn_w, bEncA, D, D, 4 * NL);
        tr(enc_ff_w1, bEncF1, D, HID, NL);
        tr(enc_ff_w2, bEncF2, HID, D, NL);
        tr(dec_attn_w, bDecA, D, D, 8 * NL);
        tr(dec_ff_w1, bDecF1, D, HID, NL);
        tr(dec_ff_w2, bDecF2, HID, D, NL);
        tr(fc_w, bFC, D, NVT, 1);
    }

    embed2_kernel<<<dim3(MROWS, 2), 128, 0, stream>>>(src, tgt, emb_src, emb_tgt,
                                                      xe, xd, xeb, xdb);

    const dim3 attn_grid(SEQ / 64, BATCH * NH);

    // ---------------- encoder ----------------
    for (int l = 0; l < NL; ++l) {
        const float* bi = enc_attn_b + (size_t)l * 4 * D;
        ushort *eA, *eF1, *eF2;
        if (batched) {
            eA = bEncA + (size_t)l * 4 * DD;
            eF1 = bEncF1 + (size_t)l * 4 * DD;
            eF2 = bEncF2 + (size_t)l * 4 * DD;
        } else {
            eA = wA; eF1 = wF1; eF2 = wF2;
            tr(enc_attn_w + (size_t)l * 4 * DD, wA, D, D, 4);
            tr(enc_ff_w1 + (size_t)l * D * HID, wF1, D, HID, 1);
            tr(enc_ff_w2 + (size_t)l * HID * D, wF2, HID, D, 1);
        }

        gemm_qkv(xeb, xeb, eA, bi);
        attn_mfma<0><<<attn_grid, 256, 0, stream>>>(qbb, kbb, vbb, src, abb);
        gemm64f(abb, eA + 3 * DD, bi + 3 * D, tb, MROWS, D, D);
        add_ln_kernel<<<MROWS, 128, 0, stream>>>(xe, xeb, tb,
            enc_ln_g + (size_t)(l * 2 + 0) * D, enc_ln_b + (size_t)(l * 2 + 0) * D);
        gemm128_relu_b(xeb, eF1, enc_ff_b1 + (size_t)l * HID, hbb, MROWS, HID, D);
        gemm64f(hbb, eF2, enc_ff_b2 + (size_t)l * D, tb, MROWS, D, HID);
        add_ln_kernel<<<MROWS, 128, 0, stream>>>(xe, xeb, tb,
            enc_ln_g + (size_t)(l * 2 + 1) * D, enc_ln_b + (size_t)(l * 2 + 1) * D);
    }

    // ---------------- decoder ----------------
    for (int l = 0; l < NL; ++l) {
        ushort *dA, *dF1, *dF2;
        if (batched) {
            dA = bDecA + (size_t)l * 8 * DD;
            dF1 = bDecF1 + (size_t)l * 4 * DD;
            dF2 = bDecF2 + (size_t)l * 4 * DD;
        } else {
            dA = wA; dF1 = wF1; dF2 = wF2;
            tr(dec_attn_w + (size_t)l * 8 * DD, wA, D, D, 8);
            tr(dec_ff_w1 + (size_t)l * D * HID, wF1, D, HID, 1);
            tr(dec_ff_w2 + (size_t)l * HID * D, wF2, HID, D, 1);
        }
        {   // self-attention (causal + tgt pad mask): slabs 0-3
            const float* bi = dec_attn_b + (size_t)(l * 2 + 0) * 4 * D;
            gemm_qkv(xdb, xdb, dA, bi);
            attn_mfma<1><<<attn_grid, 256, 0, stream>>>(qbb, kbb, vbb, tgt, abb);
            gemm64f(abb, dA + 3 * DD, bi + 3 * D, tb, MROWS, D, D);
            add_ln_kernel<<<MROWS, 128, 0, stream>>>(xd, xdb, tb,
                dec_ln_g + (size_t)(l * 3 + 0) * D, dec_ln_b + (size_t)(l * 3 + 0) * D);
        }
        {   // cross-attention: Q from xd, K/V from xe: slabs 4-7
            const float* bi = dec_attn_b + (size_t)(l * 2 + 1) * 4 * D;
            gemm_qkv(xdb, xeb, dA + 4 * DD, bi);
            attn_mfma<0><<<attn_grid, 256, 0, stream>>>(qbb, kbb, vbb, src, abb);
            gemm64f(abb, dA + 7 * DD, bi + 3 * D, tb, MROWS, D, D);
            add_ln_kernel<<<MROWS, 128, 0, stream>>>(xd, xdb, tb,
                dec_ln_g + (size_t)(l * 3 + 1) * D, dec_ln_b + (size_t)(l * 3 + 1) * D);
        }
        gemm128_relu_b(xdb, dF1, dec_ff_b1 + (size_t)l * HID, hbb, MROWS, HID, D);
        gemm64f(hbb, dF2, dec_ff_b2 + (size_t)l * D, tb, MROWS, D, HID);
        add_ln_kernel<<<MROWS, 128, 0, stream>>>(xd, xdb, tb,
            dec_ln_g + (size_t)(l * 3 + 2) * D, dec_ln_b + (size_t)(l * 3 + 2) * D);
    }

    // final projection -> logits [B*T, VT] (fp32 out)
    if (!batched) tr(fc_w, bFC, D, NVT, 1);
    {
        dim3 grid(MROWS / 128, NVT / 128, 1);
        gemm_mfma<128, 128, false, false><<<grid, 256, 0, stream>>>(xdb, xdb, bFC, fc_b, out,
                                                                    MROWS, NVT, D, 0, 0);
    }
}